// Round 1
// 2551.570 us; speedup vs baseline: 1.6243x; 1.6243x over previous
//
#include <hip/hip_runtime.h>
#include <math.h>

#define HD   512
#define H3   1536
#define SLEN 48
#define TLEN 48
#define BSZ  32
#define VOUT 32000

__device__ __forceinline__ float sigm(float x) { return 1.0f / (1.0f + __expf(-x)); }

// ---------------------------------------------------------------------------
// Generic fp32 NT GEMM: C[M,N] = act(A[M,K] @ Bt[N,K]^T + bias[N])
// Kept for the three gi precompute GEMMs (gather fused, feeds recurrence).
// ---------------------------------------------------------------------------
template <int GATHER, int ACT>
__global__ __launch_bounds__(256) void gemm_nt(
    const float* __restrict__ A, const float* __restrict__ emb,
    const int* __restrict__ tokens, const float* __restrict__ Bt,
    const float* __restrict__ bias, float* __restrict__ Cout,
    int M, int N, int K)
{
    __shared__ float As[16][68];
    __shared__ float Bs[16][68];
    const int tx = threadIdx.x, ty = threadIdx.y;
    const int tid = ty * 16 + tx;
    const int lm = tid >> 4;   // 0..15
    const int lk = tid & 15;   // 0..15
    const int m0 = blockIdx.y * 64, n0 = blockIdx.x * 64;

    const float* arow[4];
#pragma unroll
    for (int i = 0; i < 4; i++) {
        int row = m0 + lm + 16 * i;
        if (GATHER == 0) {
            arow[i] = A + (size_t)row * K;
        } else if (GATHER == 1) {
            arow[i] = emb + (size_t)tokens[row] * K;
        } else {
            int t = row >> 5, b = row & 31;
            int tok = (t == 0) ? 1 : tokens[(t - 1) * 32 + b];
            arow[i] = emb + (size_t)tok * K;
        }
    }
    const float* brow[4];
#pragma unroll
    for (int i = 0; i < 4; i++) brow[i] = Bt + (size_t)(n0 + lm + 16 * i) * K;

    float acc[4][4] = {};

    for (int kt = 0; kt < K; kt += 16) {
#pragma unroll
        for (int i = 0; i < 4; i++) {
            As[lk][lm + 16 * i] = arow[i][kt + lk];
            Bs[lk][lm + 16 * i] = brow[i][kt + lk];
        }
        __syncthreads();
#pragma unroll
        for (int k = 0; k < 16; k++) {
            float a[4], b[4];
#pragma unroll
            for (int i = 0; i < 4; i++) a[i] = As[k][ty * 4 + i];
#pragma unroll
            for (int j = 0; j < 4; j++) b[j] = Bs[k][tx * 4 + j];
#pragma unroll
            for (int i = 0; i < 4; i++)
#pragma unroll
                for (int j = 0; j < 4; j++) acc[i][j] = fmaf(a[i], b[j], acc[i][j]);
        }
        __syncthreads();
    }

#pragma unroll
    for (int i = 0; i < 4; i++) {
        int m = m0 + ty * 4 + i;
        int n = n0 + tx * 4;
        float4 v;
        v.x = acc[i][0] + bias[n + 0];
        v.y = acc[i][1] + bias[n + 1];
        v.z = acc[i][2] + bias[n + 2];
        v.w = acc[i][3] + bias[n + 3];
        if (ACT == 1) { v.x = tanhf(v.x); v.y = tanhf(v.y); v.z = tanhf(v.z); v.w = tanhf(v.w); }
        *(float4*)(Cout + (size_t)m * N + n) = v;
    }
}

// ---------------------------------------------------------------------------
// MFMA bf16x3-split NT GEMM: C[M,N] = act(A @ Bt^T + bias), fp32 in/out.
// A = Ah + Al (bf16 split, RNE); acc = Ah*Wh + Ah*Wl + Al*Wh (fp32 MFMA acc).
// 128x128 block, 4 waves (2x2), each wave 64x64 as 4x4 16x16x32 fragments.
// Fragments loaded DIRECTLY from global per-lane (each tile element touched by
// exactly one lane), converted in registers; no LDS, no barriers.
// Requires M%128==0, N%128==0, K%32==0.
// ---------------------------------------------------------------------------
typedef __attribute__((ext_vector_type(8))) __bf16 bf16x8;
typedef __attribute__((ext_vector_type(4))) float f32x4;

template <int ACT>
__global__ __launch_bounds__(256, 2) void gemm_mfma(
    const float* __restrict__ A, const float* __restrict__ Bt,
    const float* __restrict__ bias, float* __restrict__ Cout,
    int M, int N, int K)
{
    const int lane = threadIdx.x & 63;
    const int wave = threadIdx.x >> 6;        // 0..3
    const int wm = wave & 1, wn = wave >> 1;  // 2x2 waves of 64x64
    const int m0 = blockIdx.x * 128 + wm * 64;
    const int n0 = blockIdx.y * 128 + wn * 64;
    const int rl = lane & 15;                 // row/col within 16x16 frag
    const int kg = lane >> 4;                 // k-group 0..3 (8 elems each)

    const float* arow[4];
    const float* wrow[4];
#pragma unroll
    for (int f = 0; f < 4; f++) {
        arow[f] = A  + (size_t)(m0 + f * 16 + rl) * K + kg * 8;
        wrow[f] = Bt + (size_t)(n0 + f * 16 + rl) * K + kg * 8;
    }

    f32x4 acc[4][4] = {};

    for (int k0 = 0; k0 < K; k0 += 32) {
        bf16x8 ah[4], al[4], wh[4], wl[4];
#pragma unroll
        for (int f = 0; f < 4; f++) {
            float4 x0 = *(const float4*)(arow[f] + k0);
            float4 x1 = *(const float4*)(arow[f] + k0 + 4);
            float4 y0 = *(const float4*)(wrow[f] + k0);
            float4 y1 = *(const float4*)(wrow[f] + k0 + 4);
            float xs[8] = {x0.x, x0.y, x0.z, x0.w, x1.x, x1.y, x1.z, x1.w};
            float ys[8] = {y0.x, y0.y, y0.z, y0.w, y1.x, y1.y, y1.z, y1.w};
            bf16x8 xh, xl, yh, yl;
#pragma unroll
            for (int j = 0; j < 8; j++) {
                __bf16 hb = (__bf16)xs[j];
                xh[j] = hb;
                xl[j] = (__bf16)(xs[j] - (float)hb);
                __bf16 hc = (__bf16)ys[j];
                yh[j] = hc;
                yl[j] = (__bf16)(ys[j] - (float)hc);
            }
            ah[f] = xh; al[f] = xl; wh[f] = yh; wl[f] = yl;
        }
#pragma unroll
        for (int fm = 0; fm < 4; fm++)
#pragma unroll
            for (int fn = 0; fn < 4; fn++) {
                acc[fm][fn] = __builtin_amdgcn_mfma_f32_16x16x32_bf16(
                    ah[fm], wh[fn], acc[fm][fn], 0, 0, 0);
                acc[fm][fn] = __builtin_amdgcn_mfma_f32_16x16x32_bf16(
                    ah[fm], wl[fn], acc[fm][fn], 0, 0, 0);
                acc[fm][fn] = __builtin_amdgcn_mfma_f32_16x16x32_bf16(
                    al[fm], wh[fn], acc[fm][fn], 0, 0, 0);
            }
    }

    // C/D layout (gfx950 16x16x32, m89-verified): col = lane&15, row = (lane>>4)*4 + reg
#pragma unroll
    for (int fn = 0; fn < 4; fn++) {
        float bb = bias[n0 + fn * 16 + rl];
#pragma unroll
        for (int fm = 0; fm < 4; fm++) {
            int mrow = m0 + fm * 16 + kg * 4;
            int ncol = n0 + fn * 16 + rl;
#pragma unroll
            for (int r = 0; r < 4; r++) {
                float v = acc[fm][fn][r] + bb;
                if (ACT == 1) v = tanhf(v);
                Cout[(size_t)(mrow + r) * N + ncol] = v;
            }
        }
    }
}

// ---------------------------------------------------------------------------
// GRU recurrence step, k-split 2-way: lanes (l, l^32) share (b,i) and each sum
// half of the 512-k dot products; combined via one shfl_xor. Halves the
// serial dependent-load/FMA chain and doubles wave count per step.
// tid layout: b = tid&31, half = (tid>>5)&1, i = tid>>6  (32768 threads).
// ---------------------------------------------------------------------------
__device__ __forceinline__ void gru_body(int tid, const float* __restrict__ GIt,
                                         const float* __restrict__ Whh,
                                         const float* __restrict__ bhh,
                                         const float* __restrict__ hprev,
                                         float* __restrict__ hout)
{
    const int b = tid & 31;
    const int half = (tid >> 5) & 1;
    const int i = tid >> 6;
    float hr = 0.f, hz = 0.f, hn = 0.f;
    if (hprev) {
        const float4* hp4 = (const float4*)(hprev + (size_t)b * HD) + half * 64;
        const float4* wr = (const float4*)(Whh + (size_t)i * HD) + half * 64;
        const float4* wz = (const float4*)(Whh + ((size_t)i + HD) * HD) + half * 64;
        const float4* wn = (const float4*)(Whh + ((size_t)i + 2 * HD) * HD) + half * 64;
#pragma unroll 8
        for (int k = 0; k < 64; k++) {
            float4 h4 = hp4[k];
            float4 a = wr[k], c = wz[k], d = wn[k];
            hr = fmaf(h4.x, a.x, hr); hr = fmaf(h4.y, a.y, hr);
            hr = fmaf(h4.z, a.z, hr); hr = fmaf(h4.w, a.w, hr);
            hz = fmaf(h4.x, c.x, hz); hz = fmaf(h4.y, c.y, hz);
            hz = fmaf(h4.z, c.z, hz); hz = fmaf(h4.w, c.w, hz);
            hn = fmaf(h4.x, d.x, hn); hn = fmaf(h4.y, d.y, hn);
            hn = fmaf(h4.z, d.z, hn); hn = fmaf(h4.w, d.w, hn);
        }
    }
    // combine k-halves (lane pairs l <-> l^32 hold same (b,i))
    hr += __shfl_xor(hr, 32, 64);
    hz += __shfl_xor(hz, 32, 64);
    hn += __shfl_xor(hn, 32, 64);

    float hpi = hprev ? hprev[(size_t)b * HD + i] : 0.f;
    float gr = GIt[(size_t)b * H3 + i] + hr + bhh[i];
    float gz = GIt[(size_t)b * H3 + HD + i] + hz + bhh[HD + i];
    float gn = GIt[(size_t)b * H3 + 2 * HD + i];
    float ghn = hn + bhh[2 * HD + i];
    float r = sigm(gr);
    float z = sigm(gz);
    float n = tanhf(gn + r * ghn);
    if (half == 0)
        hout[(size_t)b * HD + i] = (1.f - z) * n + z * hpi;
}

__global__ __launch_bounds__(256) void gru_step(
    const float* __restrict__ GIt, const float* __restrict__ Whh,
    const float* __restrict__ bhh, const float* __restrict__ hprev,
    float* __restrict__ hout)
{
    gru_body(blockIdx.x * 256 + threadIdx.x, GIt, Whh, bhh, hprev, hout);
}

// Fused fwd+bwd encoder step (blockIdx.y selects direction)
__global__ __launch_bounds__(256) void gru_step_enc(
    const float* __restrict__ GIf, const float* __restrict__ GIb,
    const float* __restrict__ Whf, const float* __restrict__ Whb,
    const float* __restrict__ bhf, const float* __restrict__ bhb,
    const float* __restrict__ hpf, const float* __restrict__ hpb,
    float* __restrict__ hof, float* __restrict__ hob)
{
    int tid = blockIdx.x * 256 + threadIdx.x;
    if (blockIdx.y == 0)
        gru_body(tid, GIf, Whf, bhf, hpf, hof);
    else
        gru_body(tid, GIb, Whb, bhb, hpb, hob);
}

// ---------------------------------------------------------------------------
// Attention: one wave per (t,b). scores over s -> softmax -> ctx.
// ---------------------------------------------------------------------------
__global__ __launch_bounds__(256) void attention(
    const float* __restrict__ H2, const float* __restrict__ ES,
    float* __restrict__ CTX)
{
    const int wid = (blockIdx.x * 256 + threadIdx.x) >> 6;   // 0..1535
    const int lane = threadIdx.x & 63;
    const int t = wid >> 5, b = wid & 31;

    const float4* q = (const float4*)(H2 + ((size_t)t * BSZ + b) * HD);
    float4 q1 = q[lane], q2 = q[lane + 64];

    float sc = -1e30f;
    for (int s = 0; s < SLEN; s++) {
        const float4* e = (const float4*)(ES + ((size_t)s * BSZ + b) * HD);
        float4 e1 = e[lane], e2 = e[lane + 64];
        float p = q1.x * e1.x + q1.y * e1.y + q1.z * e1.z + q1.w * e1.w +
                  q2.x * e2.x + q2.y * e2.y + q2.z * e2.z + q2.w * e2.w;
#pragma unroll
        for (int d = 32; d >= 1; d >>= 1) p += __shfl_xor(p, d, 64);
        if (lane == s) sc = p;
    }
    float mx = sc;
#pragma unroll
    for (int d = 32; d >= 1; d >>= 1) mx = fmaxf(mx, __shfl_xor(mx, d, 64));
    float ex = (lane < SLEN) ? __expf(sc - mx) : 0.f;
    float sum = ex;
#pragma unroll
    for (int d = 32; d >= 1; d >>= 1) sum += __shfl_xor(sum, d, 64);
    float a = ex / sum;

    float4 c1 = {0.f, 0.f, 0.f, 0.f}, c2 = {0.f, 0.f, 0.f, 0.f};
    for (int s = 0; s < SLEN; s++) {
        float as = __shfl(a, s, 64);
        const float4* e = (const float4*)(ES + ((size_t)s * BSZ + b) * HD);
        float4 e1 = e[lane], e2 = e[lane + 64];
        c1.x = fmaf(as, e1.x, c1.x); c1.y = fmaf(as, e1.y, c1.y);
        c1.z = fmaf(as, e1.z, c1.z); c1.w = fmaf(as, e1.w, c1.w);
        c2.x = fmaf(as, e2.x, c2.x); c2.y = fmaf(as, e2.y, c2.y);
        c2.z = fmaf(as, e2.z, c2.z); c2.w = fmaf(as, e2.w, c2.w);
    }
    float4* co = (float4*)(CTX + ((size_t)t * BSZ + b) * HD);
    co[lane] = c1;
    co[lane + 64] = c2;
}

// ES = Hf + Hb (float4 elementwise)
__global__ __launch_bounds__(256) void add4(const float4* __restrict__ a,
                                            const float4* __restrict__ b,
                                            float4* __restrict__ o)
{
    int i = blockIdx.x * 256 + threadIdx.x;
    float4 x = a[i], y = b[i];
    float4 r = {x.x + y.x, x.y + y.y, x.z + y.z, x.w + y.w};
    o[i] = r;
}

// CC[r, 0:512] = H2[r], CC[r, 512:1024] = CTX[r]
__global__ __launch_bounds__(256) void concat_k(const float4* __restrict__ H2,
                                                const float4* __restrict__ CTX,
                                                float4* __restrict__ CC)
{
    int idx = blockIdx.x * 256 + threadIdx.x;    // over 1536*256 float4
    int r = idx >> 8;
    int c4 = idx & 255;
    float4 v = (c4 < 128) ? H2[r * 128 + c4] : CTX[r * 128 + (c4 - 128)];
    CC[idx] = v;
}

// ---------------------------------------------------------------------------
extern "C" void kernel_launch(void* const* d_in, const int* in_sizes, int n_in,
                              void* d_out, int out_size, void* d_ws, size_t ws_size,
                              hipStream_t stream)
{
    const int* input_b  = (const int*)d_in[0];
    const int* target_b = (const int*)d_in[1];
    const float* enc_emb = (const float*)d_in[2];
    const float* Wih_f = (const float*)d_in[3];
    const float* Whh_f = (const float*)d_in[4];
    const float* bih_f = (const float*)d_in[5];
    const float* bhh_f = (const float*)d_in[6];
    const float* Wih_b = (const float*)d_in[7];
    const float* Whh_b = (const float*)d_in[8];
    const float* bih_b = (const float*)d_in[9];
    const float* bhh_b = (const float*)d_in[10];
    const float* dec_emb = (const float*)d_in[11];
    const float* dWih = (const float*)d_in[12];
    const float* dWhh = (const float*)d_in[13];
    const float* dbih = (const float*)d_in[14];
    const float* dbhh = (const float*)d_in[15];
    const float* Wc = (const float*)d_in[16];
    const float* bc = (const float*)d_in[17];
    const float* Wo = (const float*)d_in[18];
    const float* bo = (const float*)d_in[19];
    float* out = (float*)d_out;

    // workspace layout (floats)
    float* ws  = (float*)d_ws;
    float* GIf = ws;                     // 48*32*1536 = 2359296
    float* GIb = GIf + 2359296;          // 2359296
    float* GId = GIb + 2359296;          // 2359296
    float* Hf  = GId + 2359296;          // 48*32*512 = 786432
    float* Hb  = Hf + 786432;            // 786432
    float* H2  = Hb + 786432;            // 786432
    float* ES  = H2 + 786432;            // 786432
    float* CTX = ES + 786432;            // 786432
    // aliases over buffers that are dead by the time these are written:
    float* CC   = GIb;                   // [1536,1024] = 1572864 <= 2359296
    float* Cbuf = GIf;                   // [1536,512]  =  786432 <= 2359296

    dim3 blk(16, 16);

    // gi precompute for all timesteps (embedding gather fused into A-load)
    gemm_nt<1, 0><<<dim3(24, 24), blk, 0, stream>>>(nullptr, enc_emb, input_b,
        Wih_f, bih_f, GIf, 1536, 1536, 512);
    gemm_nt<1, 0><<<dim3(24, 24), blk, 0, stream>>>(nullptr, enc_emb, input_b,
        Wih_b, bih_b, GIb, 1536, 1536, 512);
    gemm_nt<2, 0><<<dim3(24, 24), blk, 0, stream>>>(nullptr, dec_emb, target_b,
        dWih, dbih, GId, 1536, 1536, 512);

    // encoder recurrence: fwd step t and bwd step 47-t fused per launch
    // (k-split: 32768 threads per direction)
    for (int t = 0; t < SLEN; t++) {
        int tb = SLEN - 1 - t;
        gru_step_enc<<<dim3(128, 2), 256, 0, stream>>>(
            GIf + (size_t)t * BSZ * H3, GIb + (size_t)tb * BSZ * H3,
            Whh_f, Whh_b, bhh_f, bhh_b,
            t == 0 ? nullptr : Hf + (size_t)(t - 1) * BSZ * HD,
            t == 0 ? nullptr : Hb + (size_t)(tb + 1) * BSZ * HD,
            Hf + (size_t)t * BSZ * HD, Hb + (size_t)tb * BSZ * HD);
    }

    // enc_out = Hf + Hb
    add4<<<768, 256, 0, stream>>>((const float4*)Hf, (const float4*)Hb, (float4*)ES);

    // decoder recurrence (h0 = final forward encoder state)
    for (int t = 0; t < TLEN; t++) {
        gru_step<<<128, 256, 0, stream>>>(
            GId + (size_t)t * BSZ * H3, dWhh, dbhh,
            t == 0 ? Hf + (size_t)(SLEN - 1) * BSZ * HD
                   : H2 + (size_t)(t - 1) * BSZ * HD,
            H2 + (size_t)t * BSZ * HD);
    }

    // attention for all (t,b) at once
    attention<<<384, 256, 0, stream>>>(H2, ES, CTX);

    // concat [h2, ctx] then c = tanh(CC @ Wc^T + bc)   (MFMA bf16x3)
    concat_k<<<1536, 256, 0, stream>>>((const float4*)H2, (const float4*)CTX, (float4*)CC);
    gemm_mfma<1><<<dim3(12, 4), 256, 0, stream>>>(CC, Wc, bc, Cbuf, 1536, 512, 1024);

    // logits = Cbuf @ Wo^T + bo   -> [T*B, VOUT] == output layout  (MFMA bf16x3)
    gemm_mfma<0><<<dim3(12, 250), 256, 0, stream>>>(Cbuf, Wo, bo, out, 1536, VOUT, 512);
}